// Round 10
// baseline (778.730 us; speedup 1.0000x reference)
//
#include <hip/hip_runtime.h>
#include <hip/hip_bf16.h>
#include <math.h>

// Problem constants
#define BATCH 4
#define TLEN 1024
#define DMODEL 512
#define DINNER 1024
#define NSTATE 16
#define EPSV 1e-5f
// scan chunking: 32 chunks of 32 steps; 4 lanes/channel, 4 states/lane
#define NC 32
#define CT 32
#define DSTR 36
#define LOG2E 1.44269504088896f

typedef __attribute__((ext_vector_type(8))) short bf16x8;
typedef __attribute__((ext_vector_type(4))) float f32x4;

__device__ inline unsigned short f2bf(float f) {
  union { float f; unsigned int u; } c; c.f = f;
  unsigned int u = c.u;
  return (unsigned short)((u + 0x7FFFu + ((u >> 16) & 1u)) >> 16);
}
__device__ inline float bf2f(unsigned short u) {
  union { unsigned int i; float f; } c;
  c.i = ((unsigned int)u) << 16;
  return c.f;
}

// ---------------- reduction helpers ----------------
__device__ inline float warpReduceSum(float v) {
#pragma unroll
  for (int o = 32; o > 0; o >>= 1) v += __shfl_down(v, o, 64);
  return v;
}
__device__ inline float warpReduceMax(float v) {
#pragma unroll
  for (int o = 32; o > 0; o >>= 1) v = fmaxf(v, __shfl_down(v, o, 64));
  return v;
}
__device__ inline float2 blockReduceSum2_256(float a, float b) {
  __shared__ float sma[4], smb[4];
  int lane = threadIdx.x & 63, wid = threadIdx.x >> 6;
#pragma unroll
  for (int o = 32; o > 0; o >>= 1) { a += __shfl_down(a, o, 64); b += __shfl_down(b, o, 64); }
  if (lane == 0) { sma[wid] = a; smb[wid] = b; }
  __syncthreads();
  float ra = sma[0] + sma[1] + sma[2] + sma[3];
  float rb = smb[0] + smb[1] + smb[2] + smb[3];
  __syncthreads();
  return make_float2(ra, rb);
}
__device__ inline float blockReduceSum256(float v) {
  __shared__ float sm[4];
  int lane = threadIdx.x & 63, wid = threadIdx.x >> 6;
  v = warpReduceSum(v);
  if (lane == 0) sm[wid] = v;
  __syncthreads();
  float r = sm[0] + sm[1] + sm[2] + sm[3];
  __syncthreads();
  return r;
}
__device__ inline float blockReduceMax256(float v) {
  __shared__ float sm[4];
  int lane = threadIdx.x & 63, wid = threadIdx.x >> 6;
  v = warpReduceMax(v);
  if (lane == 0) sm[wid] = v;
  __syncthreads();
  float r = fmaxf(fmaxf(sm[0], sm[1]), fmaxf(sm[2], sm[3]));
  __syncthreads();
  return r;
}
__device__ inline float blockReduceSum128(float v) {
  __shared__ float sm[2];
  int lane = threadIdx.x & 63, wid = threadIdx.x >> 6;
  v = warpReduceSum(v);
  if (lane == 0) sm[wid] = v;
  __syncthreads();
  float r = sm[0] + sm[1];
  __syncthreads();
  return r;
}

// ---------------- f32 -> bf16 cast (vectorized) ----------------
__global__ void __launch_bounds__(256)
cast_f32_bf16(const float* __restrict__ src, unsigned short* __restrict__ dst, int n) {
  int i = (blockIdx.x * 256 + threadIdx.x) * 4;
  if (i >= n) return;
  float4 v = *(const float4*)(src + i);
  dst[i + 0] = f2bf(v.x);
  dst[i + 1] = f2bf(v.y);
  dst[i + 2] = f2bf(v.z);
  dst[i + 3] = f2bf(v.w);
}

// ---------------- bf16 MFMA GEMM 128x128, split epilogue (in_proj) ----------------
#define LDP 72
__global__ void __launch_bounds__(256)
gemm_bf16_split(const unsigned short* __restrict__ A, int lda,
                const unsigned short* __restrict__ B, int ldb,
                unsigned short* __restrict__ Cx, unsigned short* __restrict__ Cz, int K) {
  __shared__ unsigned short As[128 * LDP];
  __shared__ unsigned short Bs[128 * LDP];
  const int tid = threadIdx.x;
  const int lane = tid & 63, wid = tid >> 6;
  const int wm = wid >> 1, wn = wid & 1;
  const int row0 = blockIdx.y * 128, col0 = blockIdx.x * 128;
  const int c8 = (tid & 7) * 8;
  const int r0 = tid >> 3;
  const int l15 = lane & 15, lq = lane >> 4;
  f32x4 acc[4][4] = {};
  for (int k0 = 0; k0 < K; k0 += 64) {
#pragma unroll
    for (int p = 0; p < 4; p++) {
      int row = r0 + p * 32;
      bf16x8 av = *(const bf16x8*)(A + (size_t)(row0 + row) * lda + k0 + c8);
      bf16x8 bv = *(const bf16x8*)(B + (size_t)(col0 + row) * ldb + k0 + c8);
      *(bf16x8*)(As + row * LDP + c8) = av;
      *(bf16x8*)(Bs + row * LDP + c8) = bv;
    }
    __syncthreads();
#pragma unroll
    for (int s = 0; s < 2; s++) {
      const int koff = s * 32 + lq * 8;
      bf16x8 af[4], bfr[4];
#pragma unroll
      for (int i = 0; i < 4; i++)
        af[i] = *(const bf16x8*)(As + (wm * 64 + i * 16 + l15) * LDP + koff);
#pragma unroll
      for (int j = 0; j < 4; j++)
        bfr[j] = *(const bf16x8*)(Bs + (wn * 64 + j * 16 + l15) * LDP + koff);
#pragma unroll
      for (int i = 0; i < 4; i++)
#pragma unroll
        for (int j = 0; j < 4; j++)
          acc[i][j] = __builtin_amdgcn_mfma_f32_16x16x32_bf16(af[i], bfr[j], acc[i][j], 0, 0, 0);
    }
    __syncthreads();
  }
  unsigned short* dst = (col0 < 1024) ? Cx : Cz;
  const int cb = (col0 < 1024) ? col0 : (col0 - 1024);
#pragma unroll
  for (int i = 0; i < 4; i++)
#pragma unroll
    for (int j = 0; j < 4; j++)
#pragma unroll
      for (int r = 0; r < 4; r++) {
        int row = row0 + wm * 64 + i * 16 + lq * 4 + r;
        int col = cb + wn * 64 + j * 16 + l15;
        dst[(size_t)row * 1024 + col] = f2bf(acc[i][j][r]);
      }
}

// ---------------- bf16 MFMA GEMM 128x64 tile (out_proj) ----------------
__global__ void __launch_bounds__(256)
gemm_bf16_n64(const unsigned short* __restrict__ A, int lda,
              const unsigned short* __restrict__ B, int ldb,
              float* __restrict__ C, int ldc, int K) {
  __shared__ unsigned short As[128 * LDP];
  __shared__ unsigned short Bs[64 * LDP];
  const int tid = threadIdx.x;
  const int lane = tid & 63, wid = tid >> 6;
  const int wm = wid >> 1, wn = wid & 1;
  const int row0 = blockIdx.y * 128, col0 = blockIdx.x * 64;
  const int c8 = (tid & 7) * 8;
  const int r0 = tid >> 3;
  const int l15 = lane & 15, lq = lane >> 4;
  f32x4 acc[4][2] = {};
  for (int k0 = 0; k0 < K; k0 += 64) {
#pragma unroll
    for (int p = 0; p < 4; p++) {
      int row = r0 + p * 32;
      bf16x8 av = *(const bf16x8*)(A + (size_t)(row0 + row) * lda + k0 + c8);
      *(bf16x8*)(As + row * LDP + c8) = av;
    }
#pragma unroll
    for (int p = 0; p < 2; p++) {
      int row = r0 + p * 32;
      bf16x8 bv = *(const bf16x8*)(B + (size_t)(col0 + row) * ldb + k0 + c8);
      *(bf16x8*)(Bs + row * LDP + c8) = bv;
    }
    __syncthreads();
#pragma unroll
    for (int s = 0; s < 2; s++) {
      const int koff = s * 32 + lq * 8;
      bf16x8 af[4], bfr[2];
#pragma unroll
      for (int i = 0; i < 4; i++)
        af[i] = *(const bf16x8*)(As + (wm * 64 + i * 16 + l15) * LDP + koff);
#pragma unroll
      for (int j = 0; j < 2; j++)
        bfr[j] = *(const bf16x8*)(Bs + (wn * 32 + j * 16 + l15) * LDP + koff);
#pragma unroll
      for (int i = 0; i < 4; i++)
#pragma unroll
        for (int j = 0; j < 2; j++)
          acc[i][j] = __builtin_amdgcn_mfma_f32_16x16x32_bf16(af[i], bfr[j], acc[i][j], 0, 0, 0);
    }
    __syncthreads();
  }
#pragma unroll
  for (int i = 0; i < 4; i++)
#pragma unroll
    for (int j = 0; j < 2; j++)
#pragma unroll
      for (int r = 0; r < 4; r++) {
        int row = row0 + wm * 64 + i * 16 + lq * 4 + r;
        int col = col0 + wn * 32 + j * 16 + l15;
        C[(size_t)row * ldc + col] = acc[i][j][r];
      }
}

// ---------------- bf16 MFMA GEMM 128x64 split-K (x_proj) ----------------
__global__ void __launch_bounds__(256)
gemm_bf16_n64_sk(const unsigned short* __restrict__ A, int lda,
                 const unsigned short* __restrict__ B, int ldb,
                 float* __restrict__ Cpart, int KCH) {
  __shared__ unsigned short As[128 * LDP];
  __shared__ unsigned short Bs[64 * LDP];
  const int tid = threadIdx.x;
  const int lane = tid & 63, wid = tid >> 6;
  const int wm = wid >> 1, wn = wid & 1;
  const int row0 = blockIdx.y * 128;
  const int kbase = blockIdx.z * KCH;
  float* Cz = Cpart + (size_t)blockIdx.z * 4096 * 64;
  const int c8 = (tid & 7) * 8;
  const int r0 = tid >> 3;
  const int l15 = lane & 15, lq = lane >> 4;
  f32x4 acc[4][2] = {};
  for (int k0 = 0; k0 < KCH; k0 += 64) {
#pragma unroll
    for (int p = 0; p < 4; p++) {
      int row = r0 + p * 32;
      bf16x8 av = *(const bf16x8*)(A + (size_t)(row0 + row) * lda + kbase + k0 + c8);
      *(bf16x8*)(As + row * LDP + c8) = av;
    }
#pragma unroll
    for (int p = 0; p < 2; p++) {
      int row = r0 + p * 32;
      bf16x8 bv = *(const bf16x8*)(B + (size_t)row * ldb + kbase + k0 + c8);
      *(bf16x8*)(Bs + row * LDP + c8) = bv;
    }
    __syncthreads();
#pragma unroll
    for (int s = 0; s < 2; s++) {
      const int koff = s * 32 + lq * 8;
      bf16x8 af[4], bfr[2];
#pragma unroll
      for (int i = 0; i < 4; i++)
        af[i] = *(const bf16x8*)(As + (wm * 64 + i * 16 + l15) * LDP + koff);
#pragma unroll
      for (int j = 0; j < 2; j++)
        bfr[j] = *(const bf16x8*)(Bs + (wn * 32 + j * 16 + l15) * LDP + koff);
#pragma unroll
      for (int i = 0; i < 4; i++)
#pragma unroll
        for (int j = 0; j < 2; j++)
          acc[i][j] = __builtin_amdgcn_mfma_f32_16x16x32_bf16(af[i], bfr[j], acc[i][j], 0, 0, 0);
    }
    __syncthreads();
  }
#pragma unroll
  for (int i = 0; i < 4; i++)
#pragma unroll
    for (int j = 0; j < 2; j++)
#pragma unroll
      for (int r = 0; r < 4; r++) {
        int row = row0 + wm * 64 + i * 16 + lq * 4 + r;
        int col = wn * 32 + j * 16 + l15;
        Cz[(size_t)row * 64 + col] = acc[i][j][r];
      }
}

__global__ void __launch_bounds__(256)
reduce4_kernel(const float* __restrict__ part, float* __restrict__ out, int n) {
  int i = (blockIdx.x * 256 + threadIdx.x) * 4;
  if (i >= n) return;
  float4 a = *(const float4*)(part + i);
  float4 b = *(const float4*)(part + n + i);
  float4 c = *(const float4*)(part + 2 * n + i);
  float4 d = *(const float4*)(part + 3 * n + i);
  float4 r;
  r.x = a.x + b.x + c.x + d.x;
  r.y = a.y + b.y + c.y + d.y;
  r.z = a.z + b.z + c.z + d.z;
  r.w = a.w + b.w + c.w + d.w;
  *(float4*)(out + i) = r;
}

// ---------------- causal depthwise conv (DC=4, bf16 in) ×4 channels/thread ---------
__global__ void __launch_bounds__(256)
conv_silu_kernel(const unsigned short* __restrict__ xinbf,
                 const float* __restrict__ cw,
                 const float* __restrict__ cb,
                 unsigned short* __restrict__ xcbf) {
  int idx = blockIdx.x * 256 + threadIdx.x;  // over B*T*256 quads
  int d4 = (idx & 255) * 4;
  int bt = idx >> 8;
  int t = bt & 1023;
  float4 bias4 = *(const float4*)(cb + d4);
  float a0 = bias4.x, a1 = bias4.y, a2 = bias4.z, a3 = bias4.w;
  float4 w0 = *(const float4*)(cw + (size_t)(d4 + 0) * 4);
  float4 w1 = *(const float4*)(cw + (size_t)(d4 + 1) * 4);
  float4 w2 = *(const float4*)(cw + (size_t)(d4 + 2) * 4);
  float4 w3 = *(const float4*)(cw + (size_t)(d4 + 3) * 4);
  const float k0[4] = {w0.x, w0.y, w0.z, w0.w};
  const float k1[4] = {w1.x, w1.y, w1.z, w1.w};
  const float k2[4] = {w2.x, w2.y, w2.z, w2.w};
  const float k3[4] = {w3.x, w3.y, w3.z, w3.w};
#pragma unroll
  for (int k = 0; k < 4; k++) {
    int ts = t - 3 + k;
    if (ts >= 0) {
      ushort4 xv = *(const ushort4*)(xinbf + ((size_t)bt + (ts - t)) * 1024 + d4);
      a0 = fmaf(bf2f(xv.x), k0[k], a0);
      a1 = fmaf(bf2f(xv.y), k1[k], a1);
      a2 = fmaf(bf2f(xv.z), k2[k], a2);
      a3 = fmaf(bf2f(xv.w), k3[k], a3);
    }
  }
  ushort4 outv;
  outv.x = f2bf(a0 / (1.f + __expf(-a0)));
  outv.y = f2bf(a1 / (1.f + __expf(-a1)));
  outv.z = f2bf(a2 / (1.f + __expf(-a2)));
  outv.w = f2bf(a3 / (1.f + __expf(-a3)));
  *(ushort4*)(xcbf + (size_t)bt * 1024 + d4) = outv;
}

// ---------------- chunked selective scan: pass 1 (inline dt GEMM) ----------------
// grid (NC, 16, B). Stages dbc[32x68] + dtw[64x33]; computes dt = softplus(dbc@dtw^T+b)
// into bf16 dts LDS; local scan from h=0; stores hloc + sum(dt).
__global__ void __launch_bounds__(256)
scan_part1(const unsigned short* __restrict__ xcbf,
           const float* __restrict__ dbc, const float* __restrict__ dtw,
           const float* __restrict__ dtbias, const float* __restrict__ A_log,
           float* __restrict__ hloc, float* __restrict__ sdtb) {
  __shared__ float dbcs[CT * 68];
  __shared__ float dtws[64 * 33];
  __shared__ unsigned short dts[64 * DSTR];
  __shared__ unsigned short xcs[64 * DSTR];
  const int chunk = blockIdx.x, dg = blockIdx.y, b = blockIdx.z;
  const int tid = threadIdx.x;
  const int ch = tid >> 2, q4 = (tid & 3) * 4;
  const int d = dg * 64 + ch;
  const size_t bt0 = (size_t)b * TLEN + chunk * CT;
  // stage dbc (all 64 cols), dtw tile, xc tile
  for (int i = tid; i < CT * 64; i += 256) {
    int t = i >> 6, c = i & 63;
    dbcs[t * 68 + c] = dbc[(bt0 + t) * 64 + c];
    xcs[c * DSTR + t] = xcbf[(bt0 + t) * 1024 + dg * 64 + c];
  }
  for (int i = tid; i < 64 * 32; i += 256) {
    int c = i >> 5, k = i & 31;
    dtws[c * 33 + k] = dtw[(size_t)(dg * 64 + c) * 32 + k];
  }
  __syncthreads();
  // inline dt GEMM: thread (chd = tid&63, tq = tid>>6) does 8 t's for one channel
  {
    const int chd = tid & 63, tq = tid >> 6;
    const float bias = dtbias[dg * 64 + chd];
#pragma unroll
    for (int jj = 0; jj < 8; jj++) {
      int t = tq * 8 + jj;
      float acc = bias;
#pragma unroll
      for (int k = 0; k < 32; k++)
        acc = fmaf(dbcs[t * 68 + k], dtws[chd * 33 + k], acc);
      acc = (acc > 20.f) ? acc : log1pf(__expf(acc));
      dts[chd * DSTR + t] = f2bf(acc);
    }
  }
  __syncthreads();
  float4 al = *(const float4*)&A_log[d * 16 + q4];
  float4 A;
  A.x = -__expf(al.x) * LOG2E; A.y = -__expf(al.y) * LOG2E;
  A.z = -__expf(al.z) * LOG2E; A.w = -__expf(al.w) * LOG2E;
  float4 h = {0.f, 0.f, 0.f, 0.f};
  float sdt = 0.f;
#pragma unroll
  for (int t0 = 0; t0 < CT; t0 += 4) {
    ushort4 d4 = *(const ushort4*)&dts[ch * DSTR + t0];
    ushort4 x4 = *(const ushort4*)&xcs[ch * DSTR + t0];
    const float dta[4] = {bf2f(d4.x), bf2f(d4.y), bf2f(d4.z), bf2f(d4.w)};
    const float xca[4] = {bf2f(x4.x), bf2f(x4.y), bf2f(x4.z), bf2f(x4.w)};
#pragma unroll
    for (int u = 0; u < 4; u++) {
      float dtv = dta[u];
      float4 B4 = *(const float4*)&dbcs[(t0 + u) * 68 + 32 + q4];
      float uin = dtv * xca[u];
      h.x = fmaf(exp2f(dtv * A.x), h.x, uin * B4.x);
      h.y = fmaf(exp2f(dtv * A.y), h.y, uin * B4.y);
      h.z = fmaf(exp2f(dtv * A.z), h.z, uin * B4.z);
      h.w = fmaf(exp2f(dtv * A.w), h.w, uin * B4.w);
      sdt += dtv;
    }
  }
  size_t slab = (size_t)(b * 16 + dg);
  *(float4*)&hloc[(slab * NC + chunk) * 1024 + tid * 4] = h;
  sdtb[(slab * NC + chunk) * 256 + tid] = sdt;
}

// ---------------- scan prefix: fold chunk summaries -> h0 per chunk ----------------
__global__ void __launch_bounds__(256)
scan_prefix(const float* __restrict__ A_log, const float* __restrict__ hloc,
            const float* __restrict__ sdtb, float* __restrict__ h0buf) {
  const int slab = blockIdx.x;
  const int tid = threadIdx.x;
  const int dg = slab & 15;
  const int ch = tid >> 2, q4 = (tid & 3) * 4;
  const int d = dg * 64 + ch;
  float4 al = *(const float4*)&A_log[d * 16 + q4];
  float4 A;
  A.x = -__expf(al.x) * LOG2E; A.y = -__expf(al.y) * LOG2E;
  A.z = -__expf(al.z) * LOG2E; A.w = -__expf(al.w) * LOG2E;
  float4 h = {0.f, 0.f, 0.f, 0.f};
  size_t base = (size_t)slab * NC;
  for (int c = 0; c < NC; c++) {
    *(float4*)&h0buf[(base + c) * 1024 + tid * 4] = h;
    float4 hl = *(const float4*)&hloc[(base + c) * 1024 + tid * 4];
    float s = sdtb[(base + c) * 256 + tid];
    h.x = fmaf(exp2f(s * A.x), h.x, hl.x);
    h.y = fmaf(exp2f(s * A.y), h.y, hl.y);
    h.z = fmaf(exp2f(s * A.z), h.z, hl.z);
    h.w = fmaf(exp2f(s * A.w), h.w, hl.w);
  }
}

// ---------------- chunked selective scan: pass 2 (inline dt GEMM, h0 direct) -------
__global__ void __launch_bounds__(256)
scan_part2(const unsigned short* __restrict__ xcbf,
           const float* __restrict__ dbc, const float* __restrict__ dtw,
           const float* __restrict__ dtbias, const unsigned short* __restrict__ zbf,
           const float* __restrict__ A_log, const float* __restrict__ Dsk,
           const float* __restrict__ h0buf, unsigned short* __restrict__ ybf) {
  __shared__ float dbcs[CT * 68];
  __shared__ float poolbuf[64 * 33];  // phase A: dtw tile; phase C: ys[CT*64]
  __shared__ unsigned short dts[64 * DSTR];
  __shared__ unsigned short xcs[64 * DSTR];
  const int chunk = blockIdx.x, dg = blockIdx.y, b = blockIdx.z;
  const int tid = threadIdx.x;
  const int q = tid & 3;
  const int ch = tid >> 2, q4 = q * 4;
  const int d = dg * 64 + ch;
  const size_t bt0 = (size_t)b * TLEN + chunk * CT;
  const size_t slab = (size_t)(b * 16 + dg);
  float4 h = *(const float4*)&h0buf[(slab * NC + chunk) * 1024 + tid * 4];
  float4 al = *(const float4*)&A_log[d * 16 + q4];
  float4 A;
  A.x = -__expf(al.x) * LOG2E; A.y = -__expf(al.y) * LOG2E;
  A.z = -__expf(al.z) * LOG2E; A.w = -__expf(al.w) * LOG2E;
  // stage dbc, dtw, xc
  for (int i = tid; i < CT * 64; i += 256) {
    int t = i >> 6, c = i & 63;
    dbcs[t * 68 + c] = dbc[(bt0 + t) * 64 + c];
    xcs[c * DSTR + t] = xcbf[(bt0 + t) * 1024 + dg * 64 + c];
  }
  for (int i = tid; i < 64 * 32; i += 256) {
    int c = i >> 5, k = i & 31;
    poolbuf[c * 33 + k] = dtw[(size_t)(dg * 64 + c) * 32 + k];
  }
  __syncthreads();
  // inline dt GEMM
  {
    const int chd = tid & 63, tq = tid >> 6;
    const float bias = dtbias[dg * 64 + chd];
#pragma unroll
    for (int jj = 0; jj < 8; jj++) {
      int t = tq * 8 + jj;
      float acc = bias;
#pragma unroll
      for (int k = 0; k < 32; k++)
        acc = fmaf(dbcs[t * 68 + k], poolbuf[chd * 33 + k], acc);
      acc = (acc > 20.f) ? acc : log1pf(__expf(acc));
      dts[chd * DSTR + t] = f2bf(acc);
    }
  }
  __syncthreads();  // dtw reads done -> poolbuf becomes ys
  float* ys = poolbuf;
  const float Dv = Dsk[d];
#pragma unroll
  for (int t0 = 0; t0 < CT; t0 += 4) {
    ushort4 d4 = *(const ushort4*)&dts[ch * DSTR + t0];
    ushort4 x4 = *(const ushort4*)&xcs[ch * DSTR + t0];
    const float dta[4] = {bf2f(d4.x), bf2f(d4.y), bf2f(d4.z), bf2f(d4.w)};
    const float xca[4] = {bf2f(x4.x), bf2f(x4.y), bf2f(x4.z), bf2f(x4.w)};
#pragma unroll
    for (int u = 0; u < 4; u++) {
      float dtv = dta[u];
      float4 B4 = *(const float4*)&dbcs[(t0 + u) * 68 + 32 + q4];
      float4 C4 = *(const float4*)&dbcs[(t0 + u) * 68 + 48 + q4];
      float uin = dtv * xca[u];
      h.x = fmaf(exp2f(dtv * A.x), h.x, uin * B4.x);
      h.y = fmaf(exp2f(dtv * A.y), h.y, uin * B4.y);
      h.z = fmaf(exp2f(dtv * A.z), h.z, uin * B4.z);
      h.w = fmaf(exp2f(dtv * A.w), h.w, uin * B4.w);
      float cs = h.x * C4.x + h.y * C4.y + h.z * C4.z + h.w * C4.w;
      cs += __shfl_xor(cs, 1, 4);
      cs += __shfl_xor(cs, 2, 4);
      if (q == 0) ys[(t0 + u) * 64 + ch] = cs + xca[u] * Dv;
    }
  }
  __syncthreads();
  for (int i = tid; i < CT * 64; i += 256) {
    int t = i >> 6, c = i & 63;
    size_t bt = bt0 + t;
    float zv = bf2f(zbf[bt * 1024 + dg * 64 + c]);
    float sig = 1.f / (1.f + __expf(-zv));
    ybf[bt * 1024 + dg * 64 + c] = f2bf(ys[t * 64 + c] * (zv * sig));
  }
}

// ---------------- layernorm(D=512) + residual + optional attn score ----------------
__global__ void __launch_bounds__(256)
ln_res_kernel(const float* __restrict__ mo, const float* __restrict__ res,
              const float* __restrict__ g, const float* __restrict__ bb,
              float* __restrict__ xout, unsigned short* __restrict__ xout_bf,
              const float* __restrict__ awv, const float* __restrict__ abv,
              float* __restrict__ scores) {
  int row = blockIdx.x;
  int tid = threadIdx.x;
  size_t base = (size_t)row * 512;
  float v0 = mo[base + tid], v1 = mo[base + tid + 256];
  float2 ss = blockReduceSum2_256(v0 + v1, v0 * v0 + v1 * v1);
  float mu = ss.x * (1.f / 512.f);
  float var = ss.y * (1.f / 512.f) - mu * mu;
  float rs = rsqrtf(var + EPSV);
  float o0 = (v0 - mu) * rs * g[tid] + bb[tid] + res[base + tid];
  float o1 = (v1 - mu) * rs * g[tid + 256] + bb[tid + 256] + res[base + tid + 256];
  xout[base + tid] = o0;
  xout[base + tid + 256] = o1;
  xout_bf[base + tid] = f2bf(o0);
  xout_bf[base + tid + 256] = f2bf(o1);
  if (awv != nullptr) {
    float sp = o0 * awv[tid] + o1 * awv[tid + 256];
    float s = blockReduceSum256(sp);
    if (tid == 0) scores[row] = s + abv[0];
  }
}

// ---------------- pooling (reads bf16 x) ----------------
__global__ void __launch_bounds__(256)
softmax_t_kernel(const float* __restrict__ sc, float* __restrict__ wsm) {
  int b = blockIdx.x, tid = threadIdx.x;
  float v[4];
  float m = -INFINITY;
#pragma unroll
  for (int j = 0; j < 4; j++) { v[j] = sc[b * 1024 + tid + 256 * j]; m = fmaxf(m, v[j]); }
  m = blockReduceMax256(m);
  float s = 0.f;
#pragma unroll
  for (int j = 0; j < 4; j++) { v[j] = __expf(v[j] - m); s += v[j]; }
  s = blockReduceSum256(s);
  float inv = 1.f / s;
#pragma unroll
  for (int j = 0; j < 4; j++) wsm[b * 1024 + tid + 256 * j] = v[j] * inv;
}

__global__ void __launch_bounds__(256)
pool_partial(const unsigned short* __restrict__ x, const float* __restrict__ wsm,
             float* __restrict__ partial) {
  int tc = blockIdx.x, b = blockIdx.y, tid = threadIdx.x;
  float a0 = 0.f, a1 = 0.f;
  for (int t = tc * 32; t < tc * 32 + 32; t++) {
    float wv = wsm[b * 1024 + t];
    size_t base = ((size_t)b * 1024 + t) * 512;
    a0 = fmaf(wv, bf2f(x[base + tid]), a0);
    a1 = fmaf(wv, bf2f(x[base + tid + 256]), a1);
  }
  size_t pb = ((size_t)b * 32 + tc) * 512;
  partial[pb + tid] = a0;
  partial[pb + tid + 256] = a1;
}

__global__ void __launch_bounds__(256)
pool_reduce(const float* __restrict__ partial, float* __restrict__ pooled) {
  int b = blockIdx.x, tid = threadIdx.x;
  float a0 = 0.f, a1 = 0.f;
  for (int tc = 0; tc < 32; tc++) {
    size_t pb = ((size_t)b * 32 + tc) * 512;
    a0 += partial[pb + tid];
    a1 += partial[pb + tid + 256];
  }
  pooled[b * 512 + tid] = a0;
  pooled[b * 512 + tid + 256] = a1;
}

// ---------------- MLP head (tiny), one block per batch ----------------
__device__ inline float gelu_exact(float x) {
  return 0.5f * x * (1.f + erff(x * 0.70710678118654752f));
}
__global__ void __launch_bounds__(128)
head_kernel(const float* __restrict__ pooled,
            const float* __restrict__ h1w, const float* __restrict__ h1b,
            const float* __restrict__ g1, const float* __restrict__ b1,
            const float* __restrict__ h2w, const float* __restrict__ h2b,
            const float* __restrict__ g2, const float* __restrict__ b2,
            const float* __restrict__ h3w, const float* __restrict__ h3b,
            float* __restrict__ out) {
  int tid = threadIdx.x;
  int b = blockIdx.x;
  __shared__ float hs[128];
  float s = h1b[tid];
  const float* p = pooled + b * 512;
  for (int d = 0; d < 512; d += 4) {
    float4 pv = *(const float4*)(p + d);
    float4 wv = *(const float4*)(h1w + tid * 512 + d);
    s = fmaf(pv.x, wv.x, s); s = fmaf(pv.y, wv.y, s);
    s = fmaf(pv.z, wv.z, s); s = fmaf(pv.w, wv.w, s);
  }
  float mu = blockReduceSum128(s) * (1.f / 128.f);
  float dd = s - mu;
  float var = blockReduceSum128(dd * dd) * (1.f / 128.f);
  float v = dd * rsqrtf(var + EPSV) * g1[tid] + b1[tid];
  hs[tid] = gelu_exact(v);
  __syncthreads();
  float s2 = h2b[tid];
  for (int j = 0; j < 128; j++) s2 = fmaf(hs[j], h2w[tid * 128 + j], s2);
  float mu2 = blockReduceSum128(s2) * (1.f / 128.f);
  float d2 = s2 - mu2;
  float var2 = blockReduceSum128(d2 * d2) * (1.f / 128.f);
  float v2 = d2 * rsqrtf(var2 + EPSV) * g2[tid] + b2[tid];
  float h2v = gelu_exact(v2);
  float o = blockReduceSum128(h2v * h3w[tid]);
  if (tid == 0) out[b] = o + h3b[0];
}

// ---------------- launch ----------------
extern "C" void kernel_launch(void* const* d_in, const int* in_sizes, int n_in,
                              void* d_out, int out_size, void* d_ws, size_t ws_size,
                              hipStream_t stream) {
  (void)in_sizes; (void)n_in; (void)out_size; (void)ws_size;
  const float* x0   = (const float*)d_in[0];
  const float* inw  = (const float*)d_in[1];
  const float* cw   = (const float*)d_in[2];
  const float* cb   = (const float*)d_in[3];
  const float* xpw  = (const float*)d_in[4];
  const float* dtw  = (const float*)d_in[5];
  const float* dtb  = (const float*)d_in[6];
  const float* alog = (const float*)d_in[7];
  const float* dsk  = (const float*)d_in[8];
  const float* outw = (const float*)d_in[9];
  const float* lng  = (const float*)d_in[10];
  const float* lnb  = (const float*)d_in[11];
  const float* aw   = (const float*)d_in[12];
  const float* ab   = (const float*)d_in[13];
  const float* h1w  = (const float*)d_in[14];
  const float* h1b  = (const float*)d_in[15];
  const float* g1   = (const float*)d_in[16];
  const float* b1   = (const float*)d_in[17];
  const float* h2w  = (const float*)d_in[18];
  const float* h2b  = (const float*)d_in[19];
  const float* g2   = (const float*)d_in[20];
  const float* b2   = (const float*)d_in[21];
  const float* h3w  = (const float*)d_in[22];
  const float* h3b  = (const float*)d_in[23];

  float* ws = (float*)d_ws;
  unsigned short* xinbf = (unsigned short*)ws;              // 4194304 u
  unsigned short* zbf   = xinbf + 4194304;                  // 4194304 u
  unsigned short* xcbf  = zbf + 4194304;                    // 4194304 u
  float* dbc     = (float*)(xcbf + 4194304);                // 262144
  float* xpart   = dbc + 262144;                            // 1048576
  float* mo      = xpart + 1048576;                         // 2097152
  float* xbuf    = mo + 2097152;                            // 2097152
  float* hloc    = xbuf + 2097152;                          // 2097152
  float* sdtb    = hloc + 2097152;                          // 524288
  float* h0buf   = sdtb + 524288;                           // 2097152
  float* scores  = h0buf + 2097152;                         // 4096
  float* wsm     = scores + 4096;                           // 4096
  float* partial = wsm + 4096;                              // 65536
  float* pooled  = partial + 65536;                         // 2048
  unsigned short* abuf    = (unsigned short*)(pooled + 2048);  // 2097152 u
  unsigned short* ybf     = abuf + 2097152;                    // 4194304 u
  unsigned short* wbf_in  = ybf + 4194304;                     // 4194304 u
  unsigned short* wbf_out = wbf_in + 4194304;                  // 2097152 u
  unsigned short* wbf_xp  = wbf_out + 2097152;                 // 262144 u

  // one-time casts
  cast_f32_bf16<<<4096, 256, 0, stream>>>(inw, wbf_in, 4194304);
  cast_f32_bf16<<<2048, 256, 0, stream>>>(outw, wbf_out, 2097152);
  cast_f32_bf16<<<256, 256, 0, stream>>>(xpw, wbf_xp, 262144);
  cast_f32_bf16<<<2048, 256, 0, stream>>>(x0, abuf, 2097152);

  const float* xcur = x0;
  for (int l = 0; l < 4; l++) {
    // in_proj (bf16 MFMA, split epilogue): x-half bf16 xinbf, z-half bf16 zbf
    gemm_bf16_split<<<dim3(16, 32), 256, 0, stream>>>(
        abuf, 512, wbf_in + (size_t)l * 2048 * 512, 512, xinbf, zbf, 512);
    // depthwise conv + silu -> xcbf bf16 (4 ch/thread)
    conv_silu_kernel<<<4096, 256, 0, stream>>>(xinbf, cw + l * 4096, cb + l * 1024, xcbf);
    // x_proj (bf16 MFMA n64 split-K=4): [4096,1024] x [64,1024]^T -> dbc fp32
    gemm_bf16_n64_sk<<<dim3(1, 32, 4), 256, 0, stream>>>(
        xcbf, 1024, wbf_xp + (size_t)l * 65536, 1024, xpart, 256);
    reduce4_kernel<<<256, 256, 0, stream>>>(xpart, dbc, 262144);
    // chunked selective scan with inline dt_proj: local scans, prefix, final pass
    scan_part1<<<dim3(NC, 16, 4), 256, 0, stream>>>(
        xcbf, dbc, dtw + (size_t)l * 32768, dtb + l * 1024,
        alog + (size_t)l * 16384, hloc, sdtb);
    scan_prefix<<<64, 256, 0, stream>>>(alog + (size_t)l * 16384, hloc, sdtb, h0buf);
    scan_part2<<<dim3(NC, 16, 4), 256, 0, stream>>>(
        xcbf, dbc, dtw + (size_t)l * 32768, dtb + l * 1024, zbf,
        alog + (size_t)l * 16384, dsk + l * 1024, h0buf, ybf);
    // out_proj (bf16 MFMA n64): [4096,1024] x [512,1024]^T -> mo fp32
    gemm_bf16_n64<<<dim3(8, 32), 256, 0, stream>>>(
        ybf, 1024, wbf_out + (size_t)l * 524288, 1024, mo, 512, 1024);
    // layernorm + residual -> xbuf fp32 + abuf bf16; last layer also emits scores
    ln_res_kernel<<<4096, 256, 0, stream>>>(
        mo, xcur, lng + l * 512, lnb + l * 512, xbuf, abuf,
        (l == 3) ? aw : nullptr, ab, scores);
    xcur = xbuf;
  }
  // attention pooling + head (bf16 x reads; scores already computed)
  softmax_t_kernel<<<4, 256, 0, stream>>>(scores, wsm);
  pool_partial<<<dim3(32, 4), 256, 0, stream>>>(abuf, wsm, partial);
  pool_reduce<<<4, 256, 0, stream>>>(partial, pooled);
  head_kernel<<<4, 128, 0, stream>>>(pooled, h1w, h1b, g1, b1, h2w, h2b, g2, b2,
                                     h3w, h3b, (float*)d_out);
}

// Round 12
// 751.059 us; speedup vs baseline: 1.0368x; 1.0368x over previous
//
#include <hip/hip_runtime.h>
#include <hip/hip_bf16.h>
#include <math.h>

// Problem constants
#define BATCH 4
#define TLEN 1024
#define DMODEL 512
#define DINNER 1024
#define NSTATE 16
#define EPSV 1e-5f
// scan chunking: 32 chunks of 32 steps; 4 lanes/channel, 4 states/lane
#define NC 32
#define CT 32
#define DSTR 36
#define LOG2E 1.44269504088896f

typedef __attribute__((ext_vector_type(8))) short bf16x8;
typedef __attribute__((ext_vector_type(4))) float f32x4;

__device__ inline unsigned short f2bf(float f) {
  union { float f; unsigned int u; } c; c.f = f;
  unsigned int u = c.u;
  return (unsigned short)((u + 0x7FFFu + ((u >> 16) & 1u)) >> 16);
}
__device__ inline float bf2f(unsigned short u) {
  union { unsigned int i; float f; } c;
  c.i = ((unsigned int)u) << 16;
  return c.f;
}

// ---------------- reduction helpers ----------------
__device__ inline float warpReduceSum(float v) {
#pragma unroll
  for (int o = 32; o > 0; o >>= 1) v += __shfl_down(v, o, 64);
  return v;
}
__device__ inline float warpReduceMax(float v) {
#pragma unroll
  for (int o = 32; o > 0; o >>= 1) v = fmaxf(v, __shfl_down(v, o, 64));
  return v;
}
__device__ inline float2 blockReduceSum2_256(float a, float b) {
  __shared__ float sma[4], smb[4];
  int lane = threadIdx.x & 63, wid = threadIdx.x >> 6;
#pragma unroll
  for (int o = 32; o > 0; o >>= 1) { a += __shfl_down(a, o, 64); b += __shfl_down(b, o, 64); }
  if (lane == 0) { sma[wid] = a; smb[wid] = b; }
  __syncthreads();
  float ra = sma[0] + sma[1] + sma[2] + sma[3];
  float rb = smb[0] + smb[1] + smb[2] + smb[3];
  __syncthreads();
  return make_float2(ra, rb);
}
__device__ inline float blockReduceSum256(float v) {
  __shared__ float sm[4];
  int lane = threadIdx.x & 63, wid = threadIdx.x >> 6;
  v = warpReduceSum(v);
  if (lane == 0) sm[wid] = v;
  __syncthreads();
  float r = sm[0] + sm[1] + sm[2] + sm[3];
  __syncthreads();
  return r;
}
__device__ inline float blockReduceMax256(float v) {
  __shared__ float sm[4];
  int lane = threadIdx.x & 63, wid = threadIdx.x >> 6;
  v = warpReduceMax(v);
  if (lane == 0) sm[wid] = v;
  __syncthreads();
  float r = fmaxf(fmaxf(sm[0], sm[1]), fmaxf(sm[2], sm[3]));
  __syncthreads();
  return r;
}
__device__ inline float blockReduceSum128(float v) {
  __shared__ float sm[2];
  int lane = threadIdx.x & 63, wid = threadIdx.x >> 6;
  v = warpReduceSum(v);
  if (lane == 0) sm[wid] = v;
  __syncthreads();
  float r = sm[0] + sm[1];
  __syncthreads();
  return r;
}

// ---------------- f32 -> bf16 cast (vectorized) ----------------
__global__ void __launch_bounds__(256)
cast_f32_bf16(const float* __restrict__ src, unsigned short* __restrict__ dst, int n) {
  int i = (blockIdx.x * 256 + threadIdx.x) * 4;
  if (i >= n) return;
  float4 v = *(const float4*)(src + i);
  dst[i + 0] = f2bf(v.x);
  dst[i + 1] = f2bf(v.y);
  dst[i + 2] = f2bf(v.z);
  dst[i + 3] = f2bf(v.w);
}

// ---------------- bf16 MFMA GEMM 128x128, split epilogue (in_proj) ----------------
#define LDP 72
__global__ void __launch_bounds__(256)
gemm_bf16_split(const unsigned short* __restrict__ A, int lda,
                const unsigned short* __restrict__ B, int ldb,
                unsigned short* __restrict__ Cx, unsigned short* __restrict__ Cz, int K) {
  __shared__ unsigned short As[128 * LDP];
  __shared__ unsigned short Bs[128 * LDP];
  const int tid = threadIdx.x;
  const int lane = tid & 63, wid = tid >> 6;
  const int wm = wid >> 1, wn = wid & 1;
  const int row0 = blockIdx.y * 128, col0 = blockIdx.x * 128;
  const int c8 = (tid & 7) * 8;
  const int r0 = tid >> 3;
  const int l15 = lane & 15, lq = lane >> 4;
  f32x4 acc[4][4] = {};
  for (int k0 = 0; k0 < K; k0 += 64) {
#pragma unroll
    for (int p = 0; p < 4; p++) {
      int row = r0 + p * 32;
      bf16x8 av = *(const bf16x8*)(A + (size_t)(row0 + row) * lda + k0 + c8);
      bf16x8 bv = *(const bf16x8*)(B + (size_t)(col0 + row) * ldb + k0 + c8);
      *(bf16x8*)(As + row * LDP + c8) = av;
      *(bf16x8*)(Bs + row * LDP + c8) = bv;
    }
    __syncthreads();
#pragma unroll
    for (int s = 0; s < 2; s++) {
      const int koff = s * 32 + lq * 8;
      bf16x8 af[4], bfr[4];
#pragma unroll
      for (int i = 0; i < 4; i++)
        af[i] = *(const bf16x8*)(As + (wm * 64 + i * 16 + l15) * LDP + koff);
#pragma unroll
      for (int j = 0; j < 4; j++)
        bfr[j] = *(const bf16x8*)(Bs + (wn * 64 + j * 16 + l15) * LDP + koff);
#pragma unroll
      for (int i = 0; i < 4; i++)
#pragma unroll
        for (int j = 0; j < 4; j++)
          acc[i][j] = __builtin_amdgcn_mfma_f32_16x16x32_bf16(af[i], bfr[j], acc[i][j], 0, 0, 0);
    }
    __syncthreads();
  }
  unsigned short* dst = (col0 < 1024) ? Cx : Cz;
  const int cb = (col0 < 1024) ? col0 : (col0 - 1024);
#pragma unroll
  for (int i = 0; i < 4; i++)
#pragma unroll
    for (int j = 0; j < 4; j++)
#pragma unroll
      for (int r = 0; r < 4; r++) {
        int row = row0 + wm * 64 + i * 16 + lq * 4 + r;
        int col = cb + wn * 64 + j * 16 + l15;
        dst[(size_t)row * 1024 + col] = f2bf(acc[i][j][r]);
      }
}

// ---------------- bf16 MFMA GEMM 128x64 tile (out_proj) ----------------
__global__ void __launch_bounds__(256)
gemm_bf16_n64(const unsigned short* __restrict__ A, int lda,
              const unsigned short* __restrict__ B, int ldb,
              float* __restrict__ C, int ldc, int K) {
  __shared__ unsigned short As[128 * LDP];
  __shared__ unsigned short Bs[64 * LDP];
  const int tid = threadIdx.x;
  const int lane = tid & 63, wid = tid >> 6;
  const int wm = wid >> 1, wn = wid & 1;
  const int row0 = blockIdx.y * 128, col0 = blockIdx.x * 64;
  const int c8 = (tid & 7) * 8;
  const int r0 = tid >> 3;
  const int l15 = lane & 15, lq = lane >> 4;
  f32x4 acc[4][2] = {};
  for (int k0 = 0; k0 < K; k0 += 64) {
#pragma unroll
    for (int p = 0; p < 4; p++) {
      int row = r0 + p * 32;
      bf16x8 av = *(const bf16x8*)(A + (size_t)(row0 + row) * lda + k0 + c8);
      *(bf16x8*)(As + row * LDP + c8) = av;
    }
#pragma unroll
    for (int p = 0; p < 2; p++) {
      int row = r0 + p * 32;
      bf16x8 bv = *(const bf16x8*)(B + (size_t)(col0 + row) * ldb + k0 + c8);
      *(bf16x8*)(Bs + row * LDP + c8) = bv;
    }
    __syncthreads();
#pragma unroll
    for (int s = 0; s < 2; s++) {
      const int koff = s * 32 + lq * 8;
      bf16x8 af[4], bfr[2];
#pragma unroll
      for (int i = 0; i < 4; i++)
        af[i] = *(const bf16x8*)(As + (wm * 64 + i * 16 + l15) * LDP + koff);
#pragma unroll
      for (int j = 0; j < 2; j++)
        bfr[j] = *(const bf16x8*)(Bs + (wn * 32 + j * 16 + l15) * LDP + koff);
#pragma unroll
      for (int i = 0; i < 4; i++)
#pragma unroll
        for (int j = 0; j < 2; j++)
          acc[i][j] = __builtin_amdgcn_mfma_f32_16x16x32_bf16(af[i], bfr[j], acc[i][j], 0, 0, 0);
    }
    __syncthreads();
  }
#pragma unroll
  for (int i = 0; i < 4; i++)
#pragma unroll
    for (int j = 0; j < 2; j++)
#pragma unroll
      for (int r = 0; r < 4; r++) {
        int row = row0 + wm * 64 + i * 16 + lq * 4 + r;
        int col = col0 + wn * 32 + j * 16 + l15;
        C[(size_t)row * ldc + col] = acc[i][j][r];
      }
}

// ---------------- bf16 MFMA GEMM 128x64 split-K (x_proj) ----------------
__global__ void __launch_bounds__(256)
gemm_bf16_n64_sk(const unsigned short* __restrict__ A, int lda,
                 const unsigned short* __restrict__ B, int ldb,
                 float* __restrict__ Cpart, int KCH) {
  __shared__ unsigned short As[128 * LDP];
  __shared__ unsigned short Bs[64 * LDP];
  const int tid = threadIdx.x;
  const int lane = tid & 63, wid = tid >> 6;
  const int wm = wid >> 1, wn = wid & 1;
  const int row0 = blockIdx.y * 128;
  const int kbase = blockIdx.z * KCH;
  float* Cz = Cpart + (size_t)blockIdx.z * 4096 * 64;
  const int c8 = (tid & 7) * 8;
  const int r0 = tid >> 3;
  const int l15 = lane & 15, lq = lane >> 4;
  f32x4 acc[4][2] = {};
  for (int k0 = 0; k0 < KCH; k0 += 64) {
#pragma unroll
    for (int p = 0; p < 4; p++) {
      int row = r0 + p * 32;
      bf16x8 av = *(const bf16x8*)(A + (size_t)(row0 + row) * lda + kbase + k0 + c8);
      *(bf16x8*)(As + row * LDP + c8) = av;
    }
#pragma unroll
    for (int p = 0; p < 2; p++) {
      int row = r0 + p * 32;
      bf16x8 bv = *(const bf16x8*)(B + (size_t)row * ldb + kbase + k0 + c8);
      *(bf16x8*)(Bs + row * LDP + c8) = bv;
    }
    __syncthreads();
#pragma unroll
    for (int s = 0; s < 2; s++) {
      const int koff = s * 32 + lq * 8;
      bf16x8 af[4], bfr[2];
#pragma unroll
      for (int i = 0; i < 4; i++)
        af[i] = *(const bf16x8*)(As + (wm * 64 + i * 16 + l15) * LDP + koff);
#pragma unroll
      for (int j = 0; j < 2; j++)
        bfr[j] = *(const bf16x8*)(Bs + (wn * 32 + j * 16 + l15) * LDP + koff);
#pragma unroll
      for (int i = 0; i < 4; i++)
#pragma unroll
        for (int j = 0; j < 2; j++)
          acc[i][j] = __builtin_amdgcn_mfma_f32_16x16x32_bf16(af[i], bfr[j], acc[i][j], 0, 0, 0);
    }
    __syncthreads();
  }
#pragma unroll
  for (int i = 0; i < 4; i++)
#pragma unroll
    for (int j = 0; j < 2; j++)
#pragma unroll
      for (int r = 0; r < 4; r++) {
        int row = row0 + wm * 64 + i * 16 + lq * 4 + r;
        int col = wn * 32 + j * 16 + l15;
        Cz[(size_t)row * 64 + col] = acc[i][j][r];
      }
}

__global__ void __launch_bounds__(256)
reduce4_kernel(const float* __restrict__ part, float* __restrict__ out, int n) {
  int i = (blockIdx.x * 256 + threadIdx.x) * 4;
  if (i >= n) return;
  float4 a = *(const float4*)(part + i);
  float4 b = *(const float4*)(part + n + i);
  float4 c = *(const float4*)(part + 2 * n + i);
  float4 d = *(const float4*)(part + 3 * n + i);
  float4 r;
  r.x = a.x + b.x + c.x + d.x;
  r.y = a.y + b.y + c.y + d.y;
  r.z = a.z + b.z + c.z + d.z;
  r.w = a.w + b.w + c.w + d.w;
  *(float4*)(out + i) = r;
}

// ---------------- dt_proj: fp32 64x64 tile, K=32, softplus, bf16 out ----------------
__global__ void __launch_bounds__(256)
gemm_dt(const float* __restrict__ A, const float* __restrict__ B,
        unsigned short* __restrict__ C, const float* __restrict__ bias) {
  __shared__ __align__(16) float As[16][68];
  __shared__ __align__(16) float Bs[16][68];
  const int tid = threadIdx.x;
  const int tx = tid & 15, ty = tid >> 4;
  const int row0 = blockIdx.y * 64, col0 = blockIdx.x * 64;
  float acc[4][4] = {};
  for (int k0 = 0; k0 < 32; k0 += 16) {
#pragma unroll
    for (int i = 0; i < 4; i++) {
      int e = tid + i * 256;
      int m = e >> 4, kk = e & 15;
      As[kk][m] = A[(size_t)(row0 + m) * 64 + k0 + kk];
      Bs[kk][m] = B[(size_t)(col0 + m) * 32 + k0 + kk];
    }
    __syncthreads();
#pragma unroll
    for (int kk = 0; kk < 16; kk++) {
      float4 a4 = *(const float4*)&As[kk][ty << 2];
      float4 b4 = *(const float4*)&Bs[kk][tx << 2];
      float a[4] = {a4.x, a4.y, a4.z, a4.w};
      float b[4] = {b4.x, b4.y, b4.z, b4.w};
#pragma unroll
      for (int i = 0; i < 4; i++)
#pragma unroll
        for (int j = 0; j < 4; j++) acc[i][j] = fmaf(a[i], b[j], acc[i][j]);
    }
    __syncthreads();
  }
#pragma unroll
  for (int i = 0; i < 4; i++) {
    size_t r = row0 + (ty << 2) + i;
#pragma unroll
    for (int j = 0; j < 4; j++) {
      int c = col0 + (tx << 2) + j;
      float v = acc[i][j] + bias[c];
      v = (v > 20.f) ? v : log1pf(__expf(v));
      C[r * 1024 + c] = f2bf(v);
    }
  }
}

// ---------------- causal depthwise conv (DC=4, bf16 in) ×4 channels/thread ---------
__global__ void __launch_bounds__(256)
conv_silu_kernel(const unsigned short* __restrict__ xinbf,
                 const float* __restrict__ cw,
                 const float* __restrict__ cb,
                 unsigned short* __restrict__ xcbf) {
  int idx = blockIdx.x * 256 + threadIdx.x;  // over B*T*256 quads
  int d4 = (idx & 255) * 4;
  int bt = idx >> 8;
  int t = bt & 1023;
  float4 bias4 = *(const float4*)(cb + d4);
  float a0 = bias4.x, a1 = bias4.y, a2 = bias4.z, a3 = bias4.w;
  float4 w0 = *(const float4*)(cw + (size_t)(d4 + 0) * 4);
  float4 w1 = *(const float4*)(cw + (size_t)(d4 + 1) * 4);
  float4 w2 = *(const float4*)(cw + (size_t)(d4 + 2) * 4);
  float4 w3 = *(const float4*)(cw + (size_t)(d4 + 3) * 4);
  const float k0[4] = {w0.x, w0.y, w0.z, w0.w};
  const float k1[4] = {w1.x, w1.y, w1.z, w1.w};
  const float k2[4] = {w2.x, w2.y, w2.z, w2.w};
  const float k3[4] = {w3.x, w3.y, w3.z, w3.w};
#pragma unroll
  for (int k = 0; k < 4; k++) {
    int ts = t - 3 + k;
    if (ts >= 0) {
      ushort4 xv = *(const ushort4*)(xinbf + ((size_t)bt + (ts - t)) * 1024 + d4);
      a0 = fmaf(bf2f(xv.x), k0[k], a0);
      a1 = fmaf(bf2f(xv.y), k1[k], a1);
      a2 = fmaf(bf2f(xv.z), k2[k], a2);
      a3 = fmaf(bf2f(xv.w), k3[k], a3);
    }
  }
  ushort4 outv;
  outv.x = f2bf(a0 / (1.f + __expf(-a0)));
  outv.y = f2bf(a1 / (1.f + __expf(-a1)));
  outv.z = f2bf(a2 / (1.f + __expf(-a2)));
  outv.w = f2bf(a3 / (1.f + __expf(-a3)));
  *(ushort4*)(xcbf + (size_t)bt * 1024 + d4) = outv;
}

// ---------------- chunked selective scan: pass 1 (bf16 inputs) ----------------
__global__ void __launch_bounds__(256)
scan_part1(const unsigned short* __restrict__ dtbf, const unsigned short* __restrict__ xcbf,
           const float* __restrict__ dbc, const float* __restrict__ A_log,
           float* __restrict__ hloc, float* __restrict__ sdtb) {
  __shared__ unsigned short dts[64 * DSTR];
  __shared__ unsigned short xcs[64 * DSTR];
  __shared__ float Bsh[CT * 20];
  const int chunk = blockIdx.x, dg = blockIdx.y, b = blockIdx.z;
  const int tid = threadIdx.x;
  const int ch = tid >> 2, q4 = (tid & 3) * 4;
  const int d = dg * 64 + ch;
  const size_t bt0 = (size_t)b * TLEN + chunk * CT;
  for (int i = tid; i < CT * 64; i += 256) {
    int t = i >> 6, c = i & 63;
    size_t bt = bt0 + t;
    dts[c * DSTR + t] = dtbf[bt * 1024 + dg * 64 + c];
    xcs[c * DSTR + t] = xcbf[bt * 1024 + dg * 64 + c];
  }
  for (int i = tid; i < CT * 16; i += 256) {
    int t = i >> 4, n = i & 15;
    Bsh[t * 20 + n] = dbc[(bt0 + t) * 64 + 32 + n];
  }
  __syncthreads();
  float4 al = *(const float4*)&A_log[d * 16 + q4];
  float4 A;
  A.x = -__expf(al.x) * LOG2E; A.y = -__expf(al.y) * LOG2E;
  A.z = -__expf(al.z) * LOG2E; A.w = -__expf(al.w) * LOG2E;
  float4 h = {0.f, 0.f, 0.f, 0.f};
  float sdt = 0.f;
#pragma unroll
  for (int t0 = 0; t0 < CT; t0 += 4) {
    ushort4 d4 = *(const ushort4*)&dts[ch * DSTR + t0];
    ushort4 x4 = *(const ushort4*)&xcs[ch * DSTR + t0];
    const float dta[4] = {bf2f(d4.x), bf2f(d4.y), bf2f(d4.z), bf2f(d4.w)};
    const float xca[4] = {bf2f(x4.x), bf2f(x4.y), bf2f(x4.z), bf2f(x4.w)};
#pragma unroll
    for (int u = 0; u < 4; u++) {
      float dtv = dta[u];
      float4 B4 = *(const float4*)&Bsh[(t0 + u) * 20 + q4];
      float uin = dtv * xca[u];
      h.x = fmaf(exp2f(dtv * A.x), h.x, uin * B4.x);
      h.y = fmaf(exp2f(dtv * A.y), h.y, uin * B4.y);
      h.z = fmaf(exp2f(dtv * A.z), h.z, uin * B4.z);
      h.w = fmaf(exp2f(dtv * A.w), h.w, uin * B4.w);
      sdt += dtv;
    }
  }
  size_t slab = (size_t)(b * 16 + dg);
  *(float4*)&hloc[(slab * NC + chunk) * 1024 + tid * 4] = h;
  sdtb[(slab * NC + chunk) * 256 + tid] = sdt;
}

// ---------------- scan prefix: fold chunk summaries -> h0 per chunk ----------------
__global__ void __launch_bounds__(256)
scan_prefix(const float* __restrict__ A_log, const float* __restrict__ hloc,
            const float* __restrict__ sdtb, float* __restrict__ h0buf) {
  const int slab = blockIdx.x;
  const int tid = threadIdx.x;
  const int dg = slab & 15;
  const int ch = tid >> 2, q4 = (tid & 3) * 4;
  const int d = dg * 64 + ch;
  float4 al = *(const float4*)&A_log[d * 16 + q4];
  float4 A;
  A.x = -__expf(al.x) * LOG2E; A.y = -__expf(al.y) * LOG2E;
  A.z = -__expf(al.z) * LOG2E; A.w = -__expf(al.w) * LOG2E;
  float4 h = {0.f, 0.f, 0.f, 0.f};
  size_t base = (size_t)slab * NC;
  for (int c = 0; c < NC; c++) {
    *(float4*)&h0buf[(base + c) * 1024 + tid * 4] = h;
    float4 hl = *(const float4*)&hloc[(base + c) * 1024 + tid * 4];
    float s = sdtb[(base + c) * 256 + tid];
    h.x = fmaf(exp2f(s * A.x), h.x, hl.x);
    h.y = fmaf(exp2f(s * A.y), h.y, hl.y);
    h.z = fmaf(exp2f(s * A.z), h.z, hl.z);
    h.w = fmaf(exp2f(s * A.w), h.w, hl.w);
  }
}

// ---------------- chunked selective scan: pass 2 (bf16 inputs, h0 direct) ----------
__global__ void __launch_bounds__(256)
scan_part2(const unsigned short* __restrict__ dtbf, const unsigned short* __restrict__ xcbf,
           const float* __restrict__ dbc, const unsigned short* __restrict__ zbf,
           const float* __restrict__ A_log, const float* __restrict__ Dsk,
           const float* __restrict__ h0buf, unsigned short* __restrict__ ybf) {
  __shared__ unsigned short dts[64 * DSTR];
  __shared__ unsigned short xcs[64 * DSTR];
  __shared__ float Bsh[CT * 20];
  __shared__ float Csh[CT * 20];
  __shared__ float ys[CT * 64];
  const int chunk = blockIdx.x, dg = blockIdx.y, b = blockIdx.z;
  const int tid = threadIdx.x;
  const int q = tid & 3;
  const int ch = tid >> 2, q4 = q * 4;
  const int d = dg * 64 + ch;
  const size_t bt0 = (size_t)b * TLEN + chunk * CT;
  const size_t slab = (size_t)(b * 16 + dg);
  float4 h = *(const float4*)&h0buf[(slab * NC + chunk) * 1024 + tid * 4];
  float4 al = *(const float4*)&A_log[d * 16 + q4];
  float4 A;
  A.x = -__expf(al.x) * LOG2E; A.y = -__expf(al.y) * LOG2E;
  A.z = -__expf(al.z) * LOG2E; A.w = -__expf(al.w) * LOG2E;
  for (int i = tid; i < CT * 64; i += 256) {
    int t = i >> 6, c = i & 63;
    size_t bt = bt0 + t;
    dts[c * DSTR + t] = dtbf[bt * 1024 + dg * 64 + c];
    xcs[c * DSTR + t] = xcbf[bt * 1024 + dg * 64 + c];
  }
  for (int i = tid; i < CT * 16; i += 256) {
    int t = i >> 4, n = i & 15;
    Bsh[t * 20 + n] = dbc[(bt0 + t) * 64 + 32 + n];
    Csh[t * 20 + n] = dbc[(bt0 + t) * 64 + 48 + n];
  }
  __syncthreads();
  const float Dv = Dsk[d];
#pragma unroll
  for (int t0 = 0; t0 < CT; t0 += 4) {
    ushort4 d4 = *(const ushort4*)&dts[ch * DSTR + t0];
    ushort4 x4 = *(const ushort4*)&xcs[ch * DSTR + t0];
    const float dta[4] = {bf2f(d4.x), bf2f(d4.y), bf2f(d4.z), bf2f(d4.w)};
    const float xca[4] = {bf2f(x4.x), bf2f(x4.y), bf2f(x4.z), bf2f(x4.w)};
#pragma unroll
    for (int u = 0; u < 4; u++) {
      float dtv = dta[u];
      float4 B4 = *(const float4*)&Bsh[(t0 + u) * 20 + q4];
      float4 C4 = *(const float4*)&Csh[(t0 + u) * 20 + q4];
      float uin = dtv * xca[u];
      h.x = fmaf(exp2f(dtv * A.x), h.x, uin * B4.x);
      h.y = fmaf(exp2f(dtv * A.y), h.y, uin * B4.y);
      h.z = fmaf(exp2f(dtv * A.z), h.z, uin * B4.z);
      h.w = fmaf(exp2f(dtv * A.w), h.w, uin * B4.w);
      float cs = h.x * C4.x + h.y * C4.y + h.z * C4.z + h.w * C4.w;
      cs += __shfl_xor(cs, 1, 4);
      cs += __shfl_xor(cs, 2, 4);
      if (q == 0) ys[(t0 + u) * 64 + ch] = cs + xca[u] * Dv;
    }
  }
  __syncthreads();
  for (int i = tid; i < CT * 64; i += 256) {
    int t = i >> 6, c = i & 63;
    size_t bt = bt0 + t;
    float zv = bf2f(zbf[bt * 1024 + dg * 64 + c]);
    float sig = 1.f / (1.f + __expf(-zv));
    ybf[bt * 1024 + dg * 64 + c] = f2bf(ys[t * 64 + c] * (zv * sig));
  }
}

// ---------------- layernorm(D=512) + residual + optional attn score ----------------
__global__ void __launch_bounds__(256)
ln_res_kernel(const float* __restrict__ mo, const float* __restrict__ res,
              const float* __restrict__ g, const float* __restrict__ bb,
              float* __restrict__ xout, unsigned short* __restrict__ xout_bf,
              const float* __restrict__ awv, const float* __restrict__ abv,
              float* __restrict__ scores) {
  int row = blockIdx.x;
  int tid = threadIdx.x;
  size_t base = (size_t)row * 512;
  float v0 = mo[base + tid], v1 = mo[base + tid + 256];
  float2 ss = blockReduceSum2_256(v0 + v1, v0 * v0 + v1 * v1);
  float mu = ss.x * (1.f / 512.f);
  float var = ss.y * (1.f / 512.f) - mu * mu;
  float rs = rsqrtf(var + EPSV);
  float o0 = (v0 - mu) * rs * g[tid] + bb[tid] + res[base + tid];
  float o1 = (v1 - mu) * rs * g[tid + 256] + bb[tid + 256] + res[base + tid + 256];
  xout[base + tid] = o0;
  xout[base + tid + 256] = o1;
  xout_bf[base + tid] = f2bf(o0);
  xout_bf[base + tid + 256] = f2bf(o1);
  if (awv != nullptr) {
    float sp = o0 * awv[tid] + o1 * awv[tid + 256];
    float s = blockReduceSum256(sp);
    if (tid == 0) scores[row] = s + abv[0];
  }
}

// ---------------- pooling (reads bf16 x) ----------------
__global__ void __launch_bounds__(256)
softmax_t_kernel(const float* __restrict__ sc, float* __restrict__ wsm) {
  int b = blockIdx.x, tid = threadIdx.x;
  float v[4];
  float m = -INFINITY;
#pragma unroll
  for (int j = 0; j < 4; j++) { v[j] = sc[b * 1024 + tid + 256 * j]; m = fmaxf(m, v[j]); }
  m = blockReduceMax256(m);
  float s = 0.f;
#pragma unroll
  for (int j = 0; j < 4; j++) { v[j] = __expf(v[j] - m); s += v[j]; }
  s = blockReduceSum256(s);
  float inv = 1.f / s;
#pragma unroll
  for (int j = 0; j < 4; j++) wsm[b * 1024 + tid + 256 * j] = v[j] * inv;
}

__global__ void __launch_bounds__(256)
pool_partial(const unsigned short* __restrict__ x, const float* __restrict__ wsm,
             float* __restrict__ partial) {
  int tc = blockIdx.x, b = blockIdx.y, tid = threadIdx.x;
  float a0 = 0.f, a1 = 0.f;
  for (int t = tc * 32; t < tc * 32 + 32; t++) {
    float wv = wsm[b * 1024 + t];
    size_t base = ((size_t)b * 1024 + t) * 512;
    a0 = fmaf(wv, bf2f(x[base + tid]), a0);
    a1 = fmaf(wv, bf2f(x[base + tid + 256]), a1);
  }
  size_t pb = ((size_t)b * 32 + tc) * 512;
  partial[pb + tid] = a0;
  partial[pb + tid + 256] = a1;
}

__global__ void __launch_bounds__(256)
pool_reduce(const float* __restrict__ partial, float* __restrict__ pooled) {
  int b = blockIdx.x, tid = threadIdx.x;
  float a0 = 0.f, a1 = 0.f;
  for (int tc = 0; tc < 32; tc++) {
    size_t pb = ((size_t)b * 32 + tc) * 512;
    a0 += partial[pb + tid];
    a1 += partial[pb + tid + 256];
  }
  pooled[b * 512 + tid] = a0;
  pooled[b * 512 + tid + 256] = a1;
}

// ---------------- MLP head (tiny), one block per batch ----------------
__device__ inline float gelu_exact(float x) {
  return 0.5f * x * (1.f + erff(x * 0.70710678118654752f));
}
__global__ void __launch_bounds__(128)
head_kernel(const float* __restrict__ pooled,
            const float* __restrict__ h1w, const float* __restrict__ h1b,
            const float* __restrict__ g1, const float* __restrict__ b1,
            const float* __restrict__ h2w, const float* __restrict__ h2b,
            const float* __restrict__ g2, const float* __restrict__ b2,
            const float* __restrict__ h3w, const float* __restrict__ h3b,
            float* __restrict__ out) {
  int tid = threadIdx.x;
  int b = blockIdx.x;
  __shared__ float hs[128];
  float s = h1b[tid];
  const float* p = pooled + b * 512;
  for (int d = 0; d < 512; d += 4) {
    float4 pv = *(const float4*)(p + d);
    float4 wv = *(const float4*)(h1w + tid * 512 + d);
    s = fmaf(pv.x, wv.x, s); s = fmaf(pv.y, wv.y, s);
    s = fmaf(pv.z, wv.z, s); s = fmaf(pv.w, wv.w, s);
  }
  float mu = blockReduceSum128(s) * (1.f / 128.f);
  float dd = s - mu;
  float var = blockReduceSum128(dd * dd) * (1.f / 128.f);
  float v = dd * rsqrtf(var + EPSV) * g1[tid] + b1[tid];
  hs[tid] = gelu_exact(v);
  __syncthreads();
  float s2 = h2b[tid];
  for (int j = 0; j < 128; j++) s2 = fmaf(hs[j], h2w[tid * 128 + j], s2);
  float mu2 = blockReduceSum128(s2) * (1.f / 128.f);
  float d2 = s2 - mu2;
  float var2 = blockReduceSum128(d2 * d2) * (1.f / 128.f);
  float v2 = d2 * rsqrtf(var2 + EPSV) * g2[tid] + b2[tid];
  float h2v = gelu_exact(v2);
  float o = blockReduceSum128(h2v * h3w[tid]);
  if (tid == 0) out[b] = o + h3b[0];
}

// ---------------- launch ----------------
extern "C" void kernel_launch(void* const* d_in, const int* in_sizes, int n_in,
                              void* d_out, int out_size, void* d_ws, size_t ws_size,
                              hipStream_t stream) {
  (void)in_sizes; (void)n_in; (void)out_size; (void)ws_size;
  const float* x0   = (const float*)d_in[0];
  const float* inw  = (const float*)d_in[1];
  const float* cw   = (const float*)d_in[2];
  const float* cb   = (const float*)d_in[3];
  const float* xpw  = (const float*)d_in[4];
  const float* dtw  = (const float*)d_in[5];
  const float* dtb  = (const float*)d_in[6];
  const float* alog = (const float*)d_in[7];
  const float* dsk  = (const float*)d_in[8];
  const float* outw = (const float*)d_in[9];
  const float* lng  = (const float*)d_in[10];
  const float* lnb  = (const float*)d_in[11];
  const float* aw   = (const float*)d_in[12];
  const float* ab   = (const float*)d_in[13];
  const float* h1w  = (const float*)d_in[14];
  const float* h1b  = (const float*)d_in[15];
  const float* g1   = (const float*)d_in[16];
  const float* b1   = (const float*)d_in[17];
  const float* h2w  = (const float*)d_in[18];
  const float* h2b  = (const float*)d_in[19];
  const float* g2   = (const float*)d_in[20];
  const float* b2   = (const float*)d_in[21];
  const float* h3w  = (const float*)d_in[22];
  const float* h3b  = (const float*)d_in[23];

  float* ws = (float*)d_ws;
  unsigned short* xinbf = (unsigned short*)ws;              // 4194304 u
  unsigned short* zbf   = xinbf + 4194304;                  // 4194304 u
  unsigned short* xcbf  = zbf + 4194304;                    // 4194304 u
  unsigned short* dtbf  = xcbf + 4194304;                   // 4194304 u
  float* dbc     = (float*)(dtbf + 4194304);                // 262144
  float* xpart   = dbc + 262144;                            // 1048576
  float* mo      = xpart + 1048576;                         // 2097152
  float* xbuf    = mo + 2097152;                            // 2097152
  float* hloc    = xbuf + 2097152;                          // 2097152
  float* sdtb    = hloc + 2097152;                          // 524288
  float* h0buf   = sdtb + 524288;                           // 2097152
  float* scores  = h0buf + 2097152;                         // 4096
  float* wsm     = scores + 4096;                           // 4096
  float* partial = wsm + 4096;                              // 65536
  float* pooled  = partial + 65536;                         // 2048
  unsigned short* abuf    = (unsigned short*)(pooled + 2048);  // 2097152 u
  unsigned short* ybf     = abuf + 2097152;                    // 4194304 u
  unsigned short* wbf_in  = ybf + 4194304;                     // 4194304 u
  unsigned short* wbf_out = wbf_in + 4194304;                  // 2097152 u
  unsigned short* wbf_xp  = wbf_out + 2097152;                 // 262144 u

  // one-time casts
  cast_f32_bf16<<<4096, 256, 0, stream>>>(inw, wbf_in, 4194304);
  cast_f32_bf16<<<2048, 256, 0, stream>>>(outw, wbf_out, 2097152);
  cast_f32_bf16<<<256, 256, 0, stream>>>(xpw, wbf_xp, 262144);
  cast_f32_bf16<<<2048, 256, 0, stream>>>(x0, abuf, 2097152);

  const float* xcur = x0;
  for (int l = 0; l < 4; l++) {
    // in_proj (bf16 MFMA, split epilogue): x-half bf16 xinbf, z-half bf16 zbf
    gemm_bf16_split<<<dim3(16, 32), 256, 0, stream>>>(
        abuf, 512, wbf_in + (size_t)l * 2048 * 512, 512, xinbf, zbf, 512);
    // depthwise conv + silu -> xcbf bf16 (4 ch/thread)
    conv_silu_kernel<<<4096, 256, 0, stream>>>(xinbf, cw + l * 4096, cb + l * 1024, xcbf);
    // x_proj (bf16 MFMA n64 split-K=4): [4096,1024] x [64,1024]^T -> dbc fp32
    gemm_bf16_n64_sk<<<dim3(1, 32, 4), 256, 0, stream>>>(
        xcbf, 1024, wbf_xp + (size_t)l * 65536, 1024, xpart, 256);
    reduce4_kernel<<<256, 256, 0, stream>>>(xpart, dbc, 262144);
    // dt_proj + softplus -> dtbf bf16
    gemm_dt<<<dim3(16, 64), 256, 0, stream>>>(
        dbc, dtw + (size_t)l * 32768, dtbf, dtb + l * 1024);
    // chunked selective scan: local scans, prefix fold, final pass
    scan_part1<<<dim3(NC, 16, 4), 256, 0, stream>>>(
        dtbf, xcbf, dbc, alog + (size_t)l * 16384, hloc, sdtb);
    scan_prefix<<<64, 256, 0, stream>>>(alog + (size_t)l * 16384, hloc, sdtb, h0buf);
    scan_part2<<<dim3(NC, 16, 4), 256, 0, stream>>>(
        dtbf, xcbf, dbc, zbf, alog + (size_t)l * 16384, dsk + l * 1024, h0buf, ybf);
    // out_proj (bf16 MFMA n64): [4096,1024] x [512,1024]^T -> mo fp32
    gemm_bf16_n64<<<dim3(8, 32), 256, 0, stream>>>(
        ybf, 1024, wbf_out + (size_t)l * 524288, 1024, mo, 512, 1024);
    // layernorm + residual -> xbuf fp32 + abuf bf16; last layer also emits scores
    ln_res_kernel<<<4096, 256, 0, stream>>>(
        mo, xcur, lng + l * 512, lnb + l * 512, xbuf, abuf,
        (l == 3) ? aw : nullptr, ab, scores);
    xcur = xbuf;
  }
  // attention pooling + head (bf16 x reads; scores already computed)
  softmax_t_kernel<<<4, 256, 0, stream>>>(scores, wsm);
  pool_partial<<<dim3(32, 4), 256, 0, stream>>>(abuf, wsm, partial);
  pool_reduce<<<4, 256, 0, stream>>>(partial, pooled);
  head_kernel<<<4, 128, 0, stream>>>(pooled, h1w, h1b, g1, b1, h2w, h2b, g2, b2,
                                     h3w, h3b, (float*)d_out);
}